// Round 19
// baseline (51.423 us; speedup 1.0000x reference)
//
#include <hip/hip_runtime.h>
#include <hip/hip_bf16.h>
#include <hip/hip_fp16.h>
#include <stdint.h>

#define NB 8
#define LQ 256
#define LK 512
#define NH 64
// 2*log2(e): folded into projections so tanh(x) = 1 - 2/(1+exp2(SCALE*x_sum))
#define SCALE 2.8853900817779268f
#define L2E 1.4426950408889634f

// ws layout (f32 slots)
#define QP_OFF   0            // [2048][64]
#define KP_OFF   131072       // [4096][64] k-proj (plain row-major)
#define VBF_OFF  393216       // [8][512][256] bf16 (524288 f32 slots)
#define PL_OFF   917504       // [2048][ns] l-sums (f32)
// pacc (f32) follows pl; [2048][ns][256]

extern "C" __device__ float __ocml_exp2_f32(float);
static __device__ __forceinline__ float fexp2(float x) {
#if __has_builtin(__builtin_amdgcn_exp2f)
  return __builtin_amdgcn_exp2f(x);
#else
  return __ocml_exp2_f32(x);
#endif
}
static __device__ __forceinline__ float frcp(float x) {
  return __builtin_amdgcn_rcpf(x);
}
static __device__ __forceinline__ uint16_t f2bf(float f) {
  uint32_t u = __float_as_uint(f);
  uint32_t r = (u + 0x7FFFu + ((u >> 16) & 1u)) >> 16;  // RNE
  return (uint16_t)r;
}

// async global->LDS, 16B per lane: dest = wave-uniform LDS base + lane*16,
// src = per-lane global address. Counts against vmcnt.
typedef const __attribute__((address_space(1))) void* gas_ptr;
typedef __attribute__((address_space(3))) void* las_ptr;
static __device__ __forceinline__ void gload16(const void* g, void* l) {
  __builtin_amdgcn_global_load_lds((gas_ptr)g, (las_ptr)l, 16, 0, 0);
}

// blocks 0..63:    q-projection -> qp[row][h] (scaled)   (32 tiles of 64 rows x 2 hh)
// blocks 64..191:  k-projection -> kp[row][h] (scaled)   (64 tiles of 64 rows x 2 hh)
// blocks 192..255: values f32 -> bf16
// 2 rows x 4 h per thread (R12 proven; Pade reverted — R18 regressed).
__global__ __launch_bounds__(256) void proj_kernel(
    const float* __restrict__ queries, const float* __restrict__ keys,
    const float* __restrict__ values,
    const float* __restrict__ Wq, const float* __restrict__ Wk,
    float* __restrict__ qp, float* __restrict__ kp, uint16_t* __restrict__ vbf)
{
  __shared__ float Wt[256][36];   // [d][h_local 0..31], pad 36 (rows 16B-aligned)
  const int blk = blockIdx.x;
  const int t = threadIdx.x;

  if (blk >= 192) {
    int base = (blk - 192) * 16384 + t * 4;
#pragma unroll
    for (int it = 0; it < 16; ++it) {
      int idx = base + it * 1024;
      float4 v = *(const float4*)(values + idx);
      uint32_t lo = (uint32_t)f2bf(v.x) | ((uint32_t)f2bf(v.y) << 16);
      uint32_t hi = (uint32_t)f2bf(v.z) | ((uint32_t)f2bf(v.w) << 16);
      uint2 pk = {lo, hi};
      *(uint2*)(vbf + idx) = pk;
    }
    return;
  }

  const bool isQ = (blk < 64);
  const int sub = isQ ? blk : (blk - 64);
  const int tile = sub >> 1;
  const int hh = (sub & 1) * 32;
  const int rowbase = tile * 64;
  const float* __restrict__ X = isQ ? queries : keys;
  const float* __restrict__ W = isQ ? Wq : Wk;
  float* __restrict__ P = isQ ? qp : kp;

#pragma unroll 4
  for (int it = 0; it < 32; ++it) {
    Wt[t][it] = W[(hh + it) * 256 + t];
  }
  __syncthreads();

  const int ty = t >> 3;          // 0..31 -> 2 rows each
  const int tx = t & 7;           // 0..7  -> 4 h each
  float a0x = 0.f, a0y = 0.f, a0z = 0.f, a0w = 0.f;
  float a1x = 0.f, a1y = 0.f, a1z = 0.f, a1w = 0.f;

  const float* xr0 = X + (size_t)(rowbase + ty * 2) * 256;
  const float* xr1 = xr0 + 256;

#pragma unroll 4
  for (int d4 = 0; d4 < 64; ++d4) {
    int d = d4 * 4;
    float4 x0 = *(const float4*)(xr0 + d);
    float4 x1 = *(const float4*)(xr1 + d);
    float4 w0 = *(const float4*)&Wt[d + 0][tx * 4];
    float4 w1 = *(const float4*)&Wt[d + 1][tx * 4];
    float4 w2 = *(const float4*)&Wt[d + 2][tx * 4];
    float4 w3 = *(const float4*)&Wt[d + 3][tx * 4];
#define STEP(XC, WD) \
    a0x = fmaf(x0.XC, WD.x, a0x); a0y = fmaf(x0.XC, WD.y, a0y); \
    a0z = fmaf(x0.XC, WD.z, a0z); a0w = fmaf(x0.XC, WD.w, a0w); \
    a1x = fmaf(x1.XC, WD.x, a1x); a1y = fmaf(x1.XC, WD.y, a1y); \
    a1z = fmaf(x1.XC, WD.z, a1z); a1w = fmaf(x1.XC, WD.w, a1w);
    STEP(x, w0) STEP(y, w1) STEP(z, w2) STEP(w, w3)
#undef STEP
  }

  {
    int row0 = rowbase + ty * 2;
    int h = hh + tx * 4;
    float4 o0 = {a0x * SCALE, a0y * SCALE, a0z * SCALE, a0w * SCALE};
    float4 o1 = {a1x * SCALE, a1y * SCALE, a1z * SCALE, a1w * SCALE};
    *(float4*)&P[(size_t)row0 * 64 + h] = o0;
    *(float4*)&P[(size_t)(row0 + 1) * 64 + h] = o1;
  }
}

// R19: KVBLK=64 — HALF the barrier-rounds at identical per-(row,k) cost.
// grid = nsplit*256 WGs of 256 thr (4 waves); nsplit=2 -> 512 WGs fully
// resident (2/CU). wg -> b=wg&7, qg=(wg>>3)&31, kh=wg>>8. Wave owns 2 rows.
// Per 64-k tile (single-buffer, 52KB LDS, 3 WGs/CU cap):
//   vmcnt(0)+barrier -> score pass row0 (lane=kj 0..63, q LDS-broadcast)
//   -> score pass row1 -> PV (lane=(half,c): kk-half x 8d, both rows)
//   -> barrier -> STAGE(next).
// FLAT exp-sum softmax (R11). R12 math (exp2-tanh) — Pade reverted (R18 -4us).
__global__ __launch_bounds__(256) void attn_kernel(
    const float* __restrict__ qp, const float* __restrict__ kp,
    const uint16_t* __restrict__ vbf, const float* __restrict__ w_v,
    const int* __restrict__ valid_lens, float* __restrict__ out,
    float* __restrict__ pl, float* __restrict__ pacc, int nsplit)
{
  __shared__ float kTs[64][64];      // [kj][h], 16B chunks XOR-swizzled by kj&7
  __shared__ uint16_t Vs[64][256];   // [kj][d] bf16, linear
  __shared__ float q_s[4][2][64];    // [w][r][h]
  __shared__ float p_s[4][2][64];    // [w][r][kj]

  const int t = threadIdx.x;
  const int lane = t & 63;
  const int w = t >> 6;
  const int half = lane >> 5;    // PV: kk-half. write: row index within pair.
  const int c = lane & 31;       // PV/write: d-chunk (8 floats)
  const int kj = lane;           // score: k index 0..63
  const int wg = blockIdx.x;
  const int b = wg & 7;
  const int qg = (wg >> 3) & 31;
  const int kh = wg >> 8;
  const int row0 = b * LQ + qg * 8 + w * 2;

  const int vl = valid_lens[b];
  const int n = (vl > 0) ? vl : LK;   // vl==0 -> uniform softmax over all 512
  const int span = LK / nsplit;
  const int kstart = kh * span;
  int cnt = n - kstart;
  if (cnt > span) cnt = span;
  const int ntiles = (cnt > 0) ? ((cnt + 63) >> 6) : 0;

  if (ntiles == 0) {          // WG-uniform (b,kh only); nsplit>1 guaranteed here
    if (c == 0) pl[(row0 + half) * nsplit + kh] = 0.f;
    float4 z = {0.f, 0.f, 0.f, 0.f};
    float* pa = pacc + ((size_t)((row0 + half) * nsplit + kh)) * 256 + c * 8;
    *(float4*)(pa + 0) = z;
    *(float4*)(pa + 4) = z;
    return;
  }

  const float* kpb = kp + (size_t)(b * LK) * 64;
  const char* vbc = (const char*)(vbf + (size_t)b * LK * 256);

  // DMA one 64-k tile: 12 gload16 per wave (k 4 + V 8). Wave w covers rows
  // w*16..w*16+15. k: lane l -> row base+(l>>4), phys chunk l&15, src chunk
  // = phys ^ (row&7) (XOR involution; LDS dest linear). V: 1KB linear/instr.
#define STAGE(K0) do { \
    int cph = lane & 15; \
    int kr0 = w * 16 + (lane >> 4); \
    gload16(kpb + (size_t)((K0) + kr0) * 64 + ((cph ^ (kr0 & 7)) << 2), \
            &kTs[w * 16][0]); \
    int kr1 = kr0 + 4; \
    gload16(kpb + (size_t)((K0) + kr1) * 64 + ((cph ^ (kr1 & 7)) << 2), \
            &kTs[w * 16 + 4][0]); \
    int kr2 = kr0 + 8; \
    gload16(kpb + (size_t)((K0) + kr2) * 64 + ((cph ^ (kr2 & 7)) << 2), \
            &kTs[w * 16 + 8][0]); \
    int kr3 = kr0 + 12; \
    gload16(kpb + (size_t)((K0) + kr3) * 64 + ((cph ^ (kr3 & 7)) << 2), \
            &kTs[w * 16 + 12][0]); \
    const char* vsrc = vbc + (size_t)((K0) + w * 16) * 512 + lane * 16; \
    gload16(vsrc + 0 * 1024, &Vs[w * 16 +  0][0]); \
    gload16(vsrc + 1 * 1024, &Vs[w * 16 +  2][0]); \
    gload16(vsrc + 2 * 1024, &Vs[w * 16 +  4][0]); \
    gload16(vsrc + 3 * 1024, &Vs[w * 16 +  6][0]); \
    gload16(vsrc + 4 * 1024, &Vs[w * 16 +  8][0]); \
    gload16(vsrc + 5 * 1024, &Vs[w * 16 + 10][0]); \
    gload16(vsrc + 6 * 1024, &Vs[w * 16 + 12][0]); \
    gload16(vsrc + 7 * 1024, &Vs[w * 16 + 14][0]); \
  } while (0)

  STAGE(kstart);     // tile-0 DMA in flight during prologue

  // stage this wave's 2 q-rows into LDS (same-wave handoff: threads
  // [w*64,(w+1)*64) write exactly q_s[w][0..1][*])
  {
    const float2* qsrc = (const float2*)(qp + (size_t)row0 * 64 - (size_t)(w * 128) + (size_t)(w * 128));
    ((float2*)q_s)[t] = ((const float2*)(qp + (size_t)(b * LQ + qg * 8) * 64))[t];
    (void)qsrc;
  }

  // W1*L2E via uniform (scalar) loads
  float W1 = 0.f;
#pragma unroll
  for (int g = 0; g < 16; ++g) {
    float4 wf = *(const float4*)(w_v + g * 4);
    W1 += (wf.x + wf.y) + (wf.z + wf.w);
  }
  const float W1L = W1 * L2E;

  float l0 = 0.f, l1 = 0.f;     // per-lane partial l per row (k-slice kj)
  float acc[16];                // [0..7] row0 partial, [8..15] row1 (this kk-half)
#pragma unroll
  for (int i = 0; i < 16; ++i) acc[i] = 0.f;

  for (int tt = 0; tt < ntiles; ++tt) {
    const int k0 = kstart + tt * 64;
    asm volatile("s_waitcnt vmcnt(0)" ::: "memory");   // tile + prologue loads landed
    __builtin_amdgcn_sched_barrier(0);
    __builtin_amdgcn_s_barrier();
    __builtin_amdgcn_sched_barrier(0);
    __builtin_amdgcn_s_setprio(1);

    const int kg = k0 + kj;
    const bool inb = (kg < n);

    // ---- score pass per row r (q broadcast from LDS, 1 addr/wave) ----
#pragma unroll
    for (int r = 0; r < 2; ++r) {
      float r0 = 0.f, r1 = 0.f, r2a = 0.f, r3 = 0.f;
#pragma unroll
      for (int g = 0; g < 16; ++g) {
        float4 kf = *(const float4*)&kTs[kj][((g ^ (kj & 7)) << 2)];
        float4 qf = *(const float4*)&q_s[w][r][g * 4];
        float4 wf = *(const float4*)(w_v + g * 4);      // uniform -> s_load
        r0  = fmaf(wf.x, frcp(1.f + fexp2(qf.x + kf.x)), r0);
        r1  = fmaf(wf.y, frcp(1.f + fexp2(qf.y + kf.y)), r1);
        r2a = fmaf(wf.z, frcp(1.f + fexp2(qf.z + kf.z)), r2a);
        r3  = fmaf(wf.w, frcp(1.f + fexp2(qf.w + kf.w)), r3);
      }
      float racc = (r0 + r1) + (r2a + r3);
      float pe = fexp2(fmaf(-SCALE, racc, W1L));   // e^{W1-2*racc}
      float p;
      if (vl == 0)   p = 1.f;
      else if (inb)  p = pe;
      else           p = 0.f;
      if (r == 0) l0 += p; else l1 += p;
      p_s[w][r][kj] = p;          // same-wave handoff (lgkmcnt by compiler)
    }

    // ---- PV: lane = (half, c): kk in [half*32,+32), d = c*8..+8, BOTH rows ----
#pragma unroll
    for (int kk4 = 0; kk4 < 8; ++kk4) {
      float4 p0 = *(const float4*)&p_s[w][0][half * 32 + kk4 * 4];  // 2 addrs/wave
      float4 p1 = *(const float4*)&p_s[w][1][half * 32 + kk4 * 4];
#pragma unroll
      for (int jj = 0; jj < 4; ++jj) {
        int kk = half * 32 + kk4 * 4 + jj;
        uint4 vv = *(const uint4*)&Vs[kk][c * 8];
        float pj0 = (jj == 0) ? p0.x : (jj == 1) ? p0.y : (jj == 2) ? p0.z : p0.w;
        float pj1 = (jj == 0) ? p1.x : (jj == 1) ? p1.y : (jj == 2) ? p1.z : p1.w;
        float f0 = __uint_as_float(vv.x << 16);
        float f1 = __uint_as_float(vv.x & 0xFFFF0000u);
        float f2 = __uint_as_float(vv.y << 16);
        float f3 = __uint_as_float(vv.y & 0xFFFF0000u);
        float f4 = __uint_as_float(vv.z << 16);
        float f5 = __uint_as_float(vv.z & 0xFFFF0000u);
        float f6 = __uint_as_float(vv.w << 16);
        float f7 = __uint_as_float(vv.w & 0xFFFF0000u);
        acc[0] = fmaf(pj0, f0, acc[0]);   acc[8]  = fmaf(pj1, f0, acc[8]);
        acc[1] = fmaf(pj0, f1, acc[1]);   acc[9]  = fmaf(pj1, f1, acc[9]);
        acc[2] = fmaf(pj0, f2, acc[2]);   acc[10] = fmaf(pj1, f2, acc[10]);
        acc[3] = fmaf(pj0, f3, acc[3]);   acc[11] = fmaf(pj1, f3, acc[11]);
        acc[4] = fmaf(pj0, f4, acc[4]);   acc[12] = fmaf(pj1, f4, acc[12]);
        acc[5] = fmaf(pj0, f5, acc[5]);   acc[13] = fmaf(pj1, f5, acc[13]);
        acc[6] = fmaf(pj0, f6, acc[6]);   acc[14] = fmaf(pj1, f6, acc[14]);
        acc[7] = fmaf(pj0, f7, acc[7]);   acc[15] = fmaf(pj1, f7, acc[15]);
      }
    }
    __builtin_amdgcn_s_setprio(0);
    __builtin_amdgcn_sched_barrier(0);
    __builtin_amdgcn_s_barrier();          // all readers done
    if (tt + 1 < ntiles) STAGE(k0 + 64);   // overwrite safe; waits at next vmcnt(0)
  }
#undef STAGE

  // combine kk-half partials (every lane -> full sums, both rows, chunk c)
#pragma unroll
  for (int i = 0; i < 16; ++i) acc[i] += __shfl_xor(acc[i], 32, 64);
  // l: full 64-lane reduce for each row
#pragma unroll
  for (int s = 32; s; s >>= 1) { l0 += __shfl_xor(l0, s, 64); l1 += __shfl_xor(l1, s, 64); }

  const float lsel = half ? l1 : l0;
  const float* accr = acc + half * 8;     // half h writes row h of the pair
  const int row = row0 + half;
  if (nsplit == 1) {
    float inv = 1.f / lsel;
    float4 o0 = {accr[0] * inv, accr[1] * inv, accr[2] * inv, accr[3] * inv};
    float4 o1 = {accr[4] * inv, accr[5] * inv, accr[6] * inv, accr[7] * inv};
    float* op = out + (size_t)row * 256 + c * 8;
    *(float4*)(op + 0) = o0;
    *(float4*)(op + 4) = o1;
  } else {
    if (c == 0) pl[row * nsplit + kh] = lsel;
    float* pa = pacc + ((size_t)(row * nsplit + kh)) * 256 + c * 8;
    float4 a0 = {accr[0], accr[1], accr[2], accr[3]};
    float4 a1 = {accr[4], accr[5], accr[6], accr[7]};
    *(float4*)(pa + 0) = a0;
    *(float4*)(pa + 4) = a1;
  }
}

// merge k-split partials: plain sums. 256 blocks x 256 thr; 8 rows/block.
__global__ __launch_bounds__(256) void merge_kernel(
    const float* __restrict__ pl, const float* __restrict__ pacc,
    float* __restrict__ out, int nsplit)
{
  const int t = threadIdx.x;
  const int row = blockIdx.x * 8 + (t >> 5);
  const int d8 = t & 31;

  float L = 0.f;
  float o[8];
#pragma unroll
  for (int i = 0; i < 8; ++i) o[i] = 0.f;

  for (int kh = 0; kh < nsplit; ++kh) {
    L += pl[row * nsplit + kh];
    const float* pa = pacc + ((size_t)(row * nsplit + kh)) * 256 + d8 * 8;
    float4 a0 = *(const float4*)(pa + 0);
    float4 a1 = *(const float4*)(pa + 4);
    o[0] += a0.x; o[1] += a0.y; o[2] += a0.z; o[3] += a0.w;
    o[4] += a1.x; o[5] += a1.y; o[6] += a1.z; o[7] += a1.w;
  }
  float inv = 1.f / L;
  float4 o0 = {o[0] * inv, o[1] * inv, o[2] * inv, o[3] * inv};
  float4 o1 = {o[4] * inv, o[5] * inv, o[6] * inv, o[7] * inv};
  float* op = out + (size_t)row * 256 + d8 * 8;
  *(float4*)(op + 0) = o0;
  *(float4*)(op + 4) = o1;
}

extern "C" void kernel_launch(void* const* d_in, const int* in_sizes, int n_in,
                              void* d_out, int out_size, void* d_ws, size_t ws_size,
                              hipStream_t stream) {
  const float* queries    = (const float*)d_in[0];
  const float* keys       = (const float*)d_in[1];
  const float* values     = (const float*)d_in[2];
  const int*   valid_lens = (const int*)d_in[3];
  const float* Wq         = (const float*)d_in[4];
  const float* Wk         = (const float*)d_in[5];
  const float* w_v        = (const float*)d_in[6];
  float* out = (float*)d_out;

  float* ws = (float*)d_ws;
  float* qp  = ws + QP_OFF;
  float* kp  = ws + KP_OFF;
  uint16_t* vbf = (uint16_t*)(ws + VBF_OFF);
  float* pl  = ws + PL_OFF;

  // bytes needed: base 3,670,016 + pl 2048*ns*4 + pacc 2048*ns*1024 (f32)
  int nsplit;
  if      (ws_size >= (size_t)PL_OFF * 4 + 2048u * 2 * 4 + 2048u * 2 * 1024) nsplit = 2;
  else nsplit = 1;
  float* pacc = pl + (size_t)2048 * nsplit;

  hipLaunchKernelGGL(proj_kernel, dim3(256), dim3(256), 0, stream,
                     queries, keys, values, Wq, Wk, qp, kp, vbf);
  hipLaunchKernelGGL(attn_kernel, dim3(nsplit * 256), dim3(256), 0, stream,
                     qp, kp, vbf, w_v, valid_lens, out, pl, pacc, nsplit);
  if (nsplit > 1) {
    hipLaunchKernelGGL(merge_kernel, dim3(256), dim3(256), 0, stream,
                       pl, pacc, out, nsplit);
  }
}

// Round 20
// 43.356 us; speedup vs baseline: 1.1861x; 1.1861x over previous
//
#include <hip/hip_runtime.h>
#include <hip/hip_bf16.h>
#include <hip/hip_fp16.h>
#include <stdint.h>

#define NB 8
#define LQ 256
#define LK 512
#define NH 64
// 2*log2(e): folded into projections so tanh(x) = 1 - 2/(1+exp2(SCALE*x_sum))
#define SCALE 2.8853900817779268f
#define L2E 1.4426950408889634f

// ws layout (f32 slots)
#define QP_OFF   0            // [2048][64]
#define KP_OFF   131072       // [4096][64] k-proj (plain row-major)
#define VBF_OFF  393216       // [8][512][256] bf16 (524288 f32 slots)
#define PL_OFF   917504       // [2048][ns] l-sums (f32)
// pacc (f32) follows pl; [2048][ns][256]

extern "C" __device__ float __ocml_exp2_f32(float);
static __device__ __forceinline__ float fexp2(float x) {
#if __has_builtin(__builtin_amdgcn_exp2f)
  return __builtin_amdgcn_exp2f(x);
#else
  return __ocml_exp2_f32(x);
#endif
}
static __device__ __forceinline__ float frcp(float x) {
  return __builtin_amdgcn_rcpf(x);
}
static __device__ __forceinline__ uint16_t f2bf(float f) {
  uint32_t u = __float_as_uint(f);
  uint32_t r = (u + 0x7FFFu + ((u >> 16) & 1u)) >> 16;  // RNE
  return (uint16_t)r;
}

// async global->LDS, 16B per lane: dest = wave-uniform LDS base + lane*16,
// src = per-lane global address. Counts against vmcnt.
typedef const __attribute__((address_space(1))) void* gas_ptr;
typedef __attribute__((address_space(3))) void* las_ptr;
static __device__ __forceinline__ void gload16(const void* g, void* l) {
  __builtin_amdgcn_global_load_lds((gas_ptr)g, (las_ptr)l, 16, 0, 0);
}

// blocks 0..63:    q-projection -> qp[row][h] (scaled)   (32 tiles of 64 rows x 2 hh)
// blocks 64..191:  k-projection -> kp[row][h] (scaled)   (64 tiles of 64 rows x 2 hh)
// blocks 192..255: values f32 -> bf16
// R12 redesign: 2 rows x 4 h per thread. Per d4 iter: 4 ds_read_b128 (Wt,
// conflict-free + ty-broadcast) + 2 global b128 (X from L2/L1, 8 lanes share
// each addr) + 32 fma.
__global__ __launch_bounds__(256) void proj_kernel(
    const float* __restrict__ queries, const float* __restrict__ keys,
    const float* __restrict__ values,
    const float* __restrict__ Wq, const float* __restrict__ Wk,
    float* __restrict__ qp, float* __restrict__ kp, uint16_t* __restrict__ vbf)
{
  __shared__ float Wt[256][36];   // [d][h_local 0..31], pad 36 (rows 16B-aligned)
  const int blk = blockIdx.x;
  const int t = threadIdx.x;

  if (blk >= 192) {
    int base = (blk - 192) * 16384 + t * 4;
#pragma unroll
    for (int it = 0; it < 16; ++it) {
      int idx = base + it * 1024;
      float4 v = *(const float4*)(values + idx);
      uint32_t lo = (uint32_t)f2bf(v.x) | ((uint32_t)f2bf(v.y) << 16);
      uint32_t hi = (uint32_t)f2bf(v.z) | ((uint32_t)f2bf(v.w) << 16);
      uint2 pk = {lo, hi};
      *(uint2*)(vbf + idx) = pk;
    }
    return;
  }

  const bool isQ = (blk < 64);
  const int sub = isQ ? blk : (blk - 64);
  const int tile = sub >> 1;
  const int hh = (sub & 1) * 32;
  const int rowbase = tile * 64;
  const float* __restrict__ X = isQ ? queries : keys;
  const float* __restrict__ W = isQ ? Wq : Wk;
  float* __restrict__ P = isQ ? qp : kp;

  // stage W[hh..hh+31][0..255] transposed into Wt[d][hl]
#pragma unroll 4
  for (int it = 0; it < 32; ++it) {
    Wt[t][it] = W[(hh + it) * 256 + t];
  }
  __syncthreads();

  const int ty = t >> 3;          // 0..31 -> 2 rows each
  const int tx = t & 7;           // 0..7  -> 4 h each
  float a0x = 0.f, a0y = 0.f, a0z = 0.f, a0w = 0.f;
  float a1x = 0.f, a1y = 0.f, a1z = 0.f, a1w = 0.f;

  const float* xr0 = X + (size_t)(rowbase + ty * 2) * 256;
  const float* xr1 = xr0 + 256;

#pragma unroll 4
  for (int d4 = 0; d4 < 64; ++d4) {
    int d = d4 * 4;
    float4 x0 = *(const float4*)(xr0 + d);
    float4 x1 = *(const float4*)(xr1 + d);
    float4 w0 = *(const float4*)&Wt[d + 0][tx * 4];
    float4 w1 = *(const float4*)&Wt[d + 1][tx * 4];
    float4 w2 = *(const float4*)&Wt[d + 2][tx * 4];
    float4 w3 = *(const float4*)&Wt[d + 3][tx * 4];
#define STEP(XC, WD) \
    a0x = fmaf(x0.XC, WD.x, a0x); a0y = fmaf(x0.XC, WD.y, a0y); \
    a0z = fmaf(x0.XC, WD.z, a0z); a0w = fmaf(x0.XC, WD.w, a0w); \
    a1x = fmaf(x1.XC, WD.x, a1x); a1y = fmaf(x1.XC, WD.y, a1y); \
    a1z = fmaf(x1.XC, WD.z, a1z); a1w = fmaf(x1.XC, WD.w, a1w);
    STEP(x, w0) STEP(y, w1) STEP(z, w2) STEP(w, w3)
#undef STEP
  }

  {
    int row0 = rowbase + ty * 2;
    int h = hh + tx * 4;
    float4 o0 = {a0x * SCALE, a0y * SCALE, a0z * SCALE, a0w * SCALE};
    float4 o1 = {a1x * SCALE, a1y * SCALE, a1z * SCALE, a1w * SCALE};
    *(float4*)&P[(size_t)row0 * 64 + h] = o0;
    *(float4*)&P[(size_t)(row0 + 1) * 64 + h] = o1;
  }
}

// grid = nsplit*256 WGs of 256 threads (4 waves). wg -> b=wg&7, qg=(wg>>3)&31,
// kh=wg>>8. WG = 8 q-rows (2/wave). FLAT exp-sum softmax (no online max):
// scores bounded |s|<=~24 -> e^s <= 2.6e10, l <= 1.3e13, safely f32.
// Partials are PLAIN SUMS -> pacc f32. k+V staged via dbuf global_load_lds,
// counted vmcnt. This is the session's best artifact (43.4us, R12).
__global__ __launch_bounds__(256) void attn_kernel(
    const float* __restrict__ qp, const float* __restrict__ kp,
    const uint16_t* __restrict__ vbf, const float* __restrict__ w_v,
    const int* __restrict__ valid_lens, float* __restrict__ out,
    float* __restrict__ pl, float* __restrict__ pacc, int nsplit)
{
  __shared__ float kTs[2][32][64];      // [buf][kj][h], 16B chunks XOR-swizzled by kj&7
  __shared__ uint16_t Vs[2][32][256];   // [buf][kj][d] bf16, linear
  __shared__ float p_s[4][2][32];

  const int t = threadIdx.x;
  const int lane = t & 63;
  const int w = t >> 6;
  const int r2 = lane >> 5;     // score: row-half. PV: kk-half. write: row-half.
  const int kx = lane & 31;     // score: k index.  PV/write: d-chunk c.
  const int wg = blockIdx.x;
  const int b = wg & 7;
  const int qg = (wg >> 3) & 31;
  const int kh = wg >> 8;
  const int row = b * LQ + qg * 8 + w * 2 + r2;

  const int vl = valid_lens[b];
  const int n = (vl > 0) ? vl : LK;   // vl==0 -> uniform softmax over all 512
  const int span = LK / nsplit;
  const int kstart = kh * span;
  int cnt = n - kstart;
  if (cnt > span) cnt = span;
  const int ntiles = (cnt > 0) ? ((cnt + 31) >> 5) : 0;

  if (ntiles == 0) {          // WG-uniform (b,kh only); nsplit>1 guaranteed here
    if (kx == 0) pl[row * nsplit + kh] = 0.f;
    float4 z = {0.f, 0.f, 0.f, 0.f};
    float* pa = pacc + ((size_t)(row * nsplit + kh)) * 256 + kx * 8;
    *(float4*)(pa + 0) = z;
    *(float4*)(pa + 4) = z;
    return;
  }

  // W1*L2E via uniform (scalar) loads
  float W1 = 0.f;
#pragma unroll
  for (int g = 0; g < 16; ++g) {
    float4 wf = *(const float4*)(w_v + g * 4);
    W1 += (wf.x + wf.y) + (wf.z + wf.w);
  }
  const float W1L = W1 * L2E;

  // q-row (pre-scaled) in registers — 64 VGPRs, static indexing only
  float qv[64];
  {
    const float* qrow = qp + (size_t)row * 64;
#pragma unroll
    for (int i = 0; i < 16; ++i) {
      float4 v = *(const float4*)(qrow + i * 4);
      qv[i * 4 + 0] = v.x; qv[i * 4 + 1] = v.y;
      qv[i * 4 + 2] = v.z; qv[i * 4 + 3] = v.w;
    }
  }

  const float* kpb = kp + (size_t)(b * LK) * 64;
  const char* vbc = (const char*)(vbf + (size_t)b * LK * 256);

  // DMA one 32-k tile into buffer BUF: exactly 6 gload16 per wave.
  // k: lane l -> row w*8+(l>>4)(+4), phys chunk l&15, src chunk = phys^(row&7)
  // (XOR involution; LDS dest linear). V: 1KB linear per instr.
#define STAGE(BUF, K0) do { \
    int i0 = w * 2; \
    int kjr0 = i0 * 4 + (lane >> 4); \
    int cph = lane & 15; \
    gload16(kpb + (size_t)((K0) + kjr0) * 64 + (cph ^ (kjr0 & 7)) * 4, \
            &kTs[BUF][i0 * 4][0]); \
    int kjr1 = kjr0 + 4; \
    gload16(kpb + (size_t)((K0) + kjr1) * 64 + (cph ^ (kjr1 & 7)) * 4, \
            &kTs[BUF][i0 * 4 + 4][0]); \
    const char* vsrc = vbc + (size_t)(K0) * 512 + (size_t)w * 4096 + lane * 16; \
    gload16(vsrc + 0 * 1024, &Vs[BUF][w * 8 + 0][0]); \
    gload16(vsrc + 1 * 1024, &Vs[BUF][w * 8 + 2][0]); \
    gload16(vsrc + 2 * 1024, &Vs[BUF][w * 8 + 4][0]); \
    gload16(vsrc + 3 * 1024, &Vs[BUF][w * 8 + 6][0]); \
  } while (0)

  float l = 0.f;                // per-lane partial l (row r2, k-slice kx)
  float acc[16];                // [0..7] row0 partial, [8..15] row1 (this kk-half)
#pragma unroll
  for (int i = 0; i < 16; ++i) acc[i] = 0.f;

  STAGE(0, kstart);

  for (int tt = 0; tt < ntiles; ++tt) {
    const int cur = tt & 1;
    const int k0 = kstart + tt * 32;
    // counted wait: issue next-tile DMA, wait only for THIS tile's 6.
    if (tt + 1 < ntiles) {
      STAGE(cur ^ 1, k0 + 32);
      asm volatile("s_waitcnt vmcnt(6)" ::: "memory");
    } else {
      asm volatile("s_waitcnt vmcnt(0)" ::: "memory");
    }
    __builtin_amdgcn_sched_barrier(0);
    __builtin_amdgcn_s_barrier();        // all waves' tile-tt portions landed
    __builtin_amdgcn_sched_barrier(0);
    __builtin_amdgcn_s_setprio(1);

    // ---- scores: lane = (r2, kx) computes row(r2)'s score at k0+kx ----
    float r0 = 0.f, r1 = 0.f, r2a = 0.f, r3 = 0.f;
#pragma unroll
    for (int g = 0; g < 16; ++g) {
      float4 kf = *(const float4*)&kTs[cur][kx][((g ^ (kx & 7)) << 2)];
      float4 wf = *(const float4*)(w_v + g * 4);        // uniform -> s_load
      r0  = fmaf(wf.x, frcp(1.f + fexp2(qv[g * 4 + 0] + kf.x)), r0);
      r1  = fmaf(wf.y, frcp(1.f + fexp2(qv[g * 4 + 1] + kf.y)), r1);
      r2a = fmaf(wf.z, frcp(1.f + fexp2(qv[g * 4 + 2] + kf.z)), r2a);
      r3  = fmaf(wf.w, frcp(1.f + fexp2(qv[g * 4 + 3] + kf.w)), r3);
    }
    float racc = (r0 + r1) + (r2a + r3);

    // p = e^{score} = exp2(W1L - SCALE*racc); masked -> 0; vl==0 -> 1
    float pe = fexp2(fmaf(-SCALE, racc, W1L));
    int kg = k0 + kx;
    float p;
    if (vl == 0)      p = 1.f;
    else if (kg < n)  p = pe;
    else              p = 0.f;

    l += p;                 // reduced across lanes once at the end
    p_s[w][r2][kx] = p;     // same-wave handoff (lgkmcnt by compiler)

    // ---- PV: lane = (r2, c): kk in [r2*16,+16), d = c*8..+8, BOTH rows ----
    const int c = kx;
#pragma unroll
    for (int i4 = 0; i4 < 4; ++i4) {
      float4 p0 = *(const float4*)&p_s[w][0][r2 * 16 + i4 * 4];   // row0 p
      float4 p1 = *(const float4*)&p_s[w][1][r2 * 16 + i4 * 4];   // row1 p
#pragma unroll
      for (int jj = 0; jj < 4; ++jj) {
        int kk = r2 * 16 + i4 * 4 + jj;
        uint4 vv = *(const uint4*)&Vs[cur][kk][c * 8];
        float pj0 = (jj == 0) ? p0.x : (jj == 1) ? p0.y : (jj == 2) ? p0.z : p0.w;
        float pj1 = (jj == 0) ? p1.x : (jj == 1) ? p1.y : (jj == 2) ? p1.z : p1.w;
        float f0 = __uint_as_float(vv.x << 16);
        float f1 = __uint_as_float(vv.x & 0xFFFF0000u);
        float f2 = __uint_as_float(vv.y << 16);
        float f3 = __uint_as_float(vv.y & 0xFFFF0000u);
        float f4 = __uint_as_float(vv.z << 16);
        float f5 = __uint_as_float(vv.z & 0xFFFF0000u);
        float f6 = __uint_as_float(vv.w << 16);
        float f7 = __uint_as_float(vv.w & 0xFFFF0000u);
        acc[0] = fmaf(pj0, f0, acc[0]);   acc[8]  = fmaf(pj1, f0, acc[8]);
        acc[1] = fmaf(pj0, f1, acc[1]);   acc[9]  = fmaf(pj1, f1, acc[9]);
        acc[2] = fmaf(pj0, f2, acc[2]);   acc[10] = fmaf(pj1, f2, acc[10]);
        acc[3] = fmaf(pj0, f3, acc[3]);   acc[11] = fmaf(pj1, f3, acc[11]);
        acc[4] = fmaf(pj0, f4, acc[4]);   acc[12] = fmaf(pj1, f4, acc[12]);
        acc[5] = fmaf(pj0, f5, acc[5]);   acc[13] = fmaf(pj1, f5, acc[13]);
        acc[6] = fmaf(pj0, f6, acc[6]);   acc[14] = fmaf(pj1, f6, acc[14]);
        acc[7] = fmaf(pj0, f7, acc[7]);   acc[15] = fmaf(pj1, f7, acc[15]);
      }
    }
    __builtin_amdgcn_s_setprio(0);
    __builtin_amdgcn_sched_barrier(0);
    __builtin_amdgcn_s_barrier();   // readers of buf[cur] done before overwrite
  }
#undef STAGE

  // combine the two kk-half partials (full sums for both rows at own d-chunk)
#pragma unroll
  for (int i = 0; i < 16; ++i) acc[i] += __shfl_xor(acc[i], 32, 64);
  // l: reduce over the 32 kx lanes within the row-half (once, not per tile)
#pragma unroll
  for (int s = 16; s; s >>= 1) l += __shfl_xor(l, s, 64);

  const float* accr = acc + r2 * 8;
  if (nsplit == 1) {
    float inv = 1.f / l;
    float4 o0 = {accr[0] * inv, accr[1] * inv, accr[2] * inv, accr[3] * inv};
    float4 o1 = {accr[4] * inv, accr[5] * inv, accr[6] * inv, accr[7] * inv};
    float* op = out + (size_t)row * 256 + kx * 8;
    *(float4*)(op + 0) = o0;
    *(float4*)(op + 4) = o1;
  } else {
    if (kx == 0) pl[row * nsplit + kh] = l;
    float* pa = pacc + ((size_t)(row * nsplit + kh)) * 256 + kx * 8;
    float4 a0 = {accr[0], accr[1], accr[2], accr[3]};
    float4 a1 = {accr[4], accr[5], accr[6], accr[7]};
    *(float4*)(pa + 0) = a0;
    *(float4*)(pa + 4) = a1;
  }
}

// merge k-split partials: plain sums (no max rescaling needed).
// 256 blocks x 256 thr; 8 rows/block, 32 lanes/row.
__global__ __launch_bounds__(256) void merge_kernel(
    const float* __restrict__ pl, const float* __restrict__ pacc,
    float* __restrict__ out, int nsplit)
{
  const int t = threadIdx.x;
  const int row = blockIdx.x * 8 + (t >> 5);
  const int d8 = t & 31;

  float L = 0.f;
  float o[8];
#pragma unroll
  for (int i = 0; i < 8; ++i) o[i] = 0.f;

  for (int kh = 0; kh < nsplit; ++kh) {
    L += pl[row * nsplit + kh];
    const float* pa = pacc + ((size_t)(row * nsplit + kh)) * 256 + d8 * 8;
    float4 a0 = *(const float4*)(pa + 0);
    float4 a1 = *(const float4*)(pa + 4);
    o[0] += a0.x; o[1] += a0.y; o[2] += a0.z; o[3] += a0.w;
    o[4] += a1.x; o[5] += a1.y; o[6] += a1.z; o[7] += a1.w;
  }
  float inv = 1.f / L;
  float4 o0 = {o[0] * inv, o[1] * inv, o[2] * inv, o[3] * inv};
  float4 o1 = {o[4] * inv, o[5] * inv, o[6] * inv, o[7] * inv};
  float* op = out + (size_t)row * 256 + d8 * 8;
  *(float4*)(op + 0) = o0;
  *(float4*)(op + 4) = o1;
}

extern "C" void kernel_launch(void* const* d_in, const int* in_sizes, int n_in,
                              void* d_out, int out_size, void* d_ws, size_t ws_size,
                              hipStream_t stream) {
  const float* queries    = (const float*)d_in[0];
  const float* keys       = (const float*)d_in[1];
  const float* values     = (const float*)d_in[2];
  const int*   valid_lens = (const int*)d_in[3];
  const float* Wq         = (const float*)d_in[4];
  const float* Wk         = (const float*)d_in[5];
  const float* w_v        = (const float*)d_in[6];
  float* out = (float*)d_out;

  float* ws = (float*)d_ws;
  float* qp  = ws + QP_OFF;
  float* kp  = ws + KP_OFF;
  uint16_t* vbf = (uint16_t*)(ws + VBF_OFF);
  float* pl  = ws + PL_OFF;

  // bytes needed: base 3,670,016 + pl 2048*ns*4 + pacc 2048*ns*1024 (f32)
  int nsplit;
  if      (ws_size >= (size_t)PL_OFF * 4 + 2048u * 4 * 4 + 2048u * 4 * 1024) nsplit = 4;
  else if (ws_size >= (size_t)PL_OFF * 4 + 2048u * 2 * 4 + 2048u * 2 * 1024) nsplit = 2;
  else nsplit = 1;
  float* pacc = pl + (size_t)2048 * nsplit;

  hipLaunchKernelGGL(proj_kernel, dim3(256), dim3(256), 0, stream,
                     queries, keys, values, Wq, Wk, qp, kp, vbf);
  hipLaunchKernelGGL(attn_kernel, dim3(nsplit * 256), dim3(256), 0, stream,
                     qp, kp, vbf, w_v, valid_lens, out, pl, pacc, nsplit);
  if (nsplit > 1) {
    hipLaunchKernelGGL(merge_kernel, dim3(256), dim3(256), 0, stream,
                       pl, pacc, out, nsplit);
  }
}